// Round 12
// baseline (3831.256 us; speedup 1.0000x reference)
//
#include <hip/hip_runtime.h>
#include <stdint.h>
#include <stddef.h>

// Routed 2-cell LSTM, B=64, S=512, E=H=256.
// Phase 1 (xproj_kernel): precompute xg[t][g][b] = routed-cell W_ih·x_t + bias.
// Phase 2 (mlstm_rec_kernel, 32 persistent wgs): recurrence with EPOCH-IN-DWORD
//   h exchange, BATCHED: h value = {bf16<<16|epoch16} dword (aligned dword =
//   single-copy atomic). Producer: LDS bounce -> 128 coalesced dwordx4 sc0 sc1
//   stores, fire-and-forget (NO ack RTT, NO flag RTT). Consumer: wave-0 polls
//   32 sentinel dwords (128B/round), then ALL threads batch-load 64KB in one
//   vmcnt(0), validate epochs in-register, per-thread retry of its single
//   2KB producer slice (rare), pack hi16 -> swizzled LDS -> 32 MFMAs/wave.
//   Update-ready MFMA row ordering (round 9). 2-parity ring is overwrite-safe
//   by the all-to-all dependency. Numerics identical to rounds 8-11.

#define BB   64
#define SS   512
#define EE   256
#define HH   256
#define G4   1024
#define NWG  32
#define TPB  512
#define TCH  32

typedef __attribute__((ext_vector_type(8))) short short8;
typedef __attribute__((ext_vector_type(4))) float f32x4;
typedef __attribute__((ext_vector_type(4))) unsigned int uint4v;

__device__ __forceinline__ unsigned short f2bf(float f){
  union { float f; unsigned u; } v; v.f = f;
  return (unsigned short)((v.u + 0x7fffu + ((v.u >> 16) & 1u)) >> 16);
}
__device__ __forceinline__ float bf2f(unsigned short s){
  union { float f; unsigned u; } v; v.u = ((unsigned)s) << 16;
  return v.f;
}
__device__ __forceinline__ int swz(int byte){ return byte ^ (((byte >> 10) & 3) << 6); }

// ws layout (bytes):
// [1024, +131072)      : h dwords {bf16<<16|epoch}, 2 parities x 16384 dwords
//                        dword index within parity: wg*512 + b*8 + jloc
// [132096, +134217728) : xg[t=512][g=1024][b=64] fp32 (routed-cell gates)
#define WS_H_OFF  1024
#define WS_XG_OFF (1024 + 131072)

__global__ void zero_ws_kernel(int* ws){
  const int n = (WS_H_OFF + 131072) / 4;
  for (int i = blockIdx.x * blockDim.x + threadIdx.x; i < n; i += gridDim.x * blockDim.x)
    ws[i] = 0;
}

// ---------------- Phase 1: x-projection GEMM ----------------
__global__ __launch_bounds__(TPB, 1)
void xproj_kernel(const int* __restrict__ input, const int* __restrict__ assign,
                  const float* __restrict__ emb, const float* __restrict__ Wih,
                  const float* __restrict__ bih, const float* __restrict__ bhh,
                  float* __restrict__ xg)
{
  __shared__ __align__(16) unsigned short sXp[8][4][4][16][8];
  __shared__ int sTokP[TCH][64];
  __shared__ int sAsgP[TCH][64];

  const int tid  = threadIdx.x;
  const int lane = tid & 63;
  const int lg   = lane >> 4;
  const int lc   = lane & 15;
  const int wv   = tid >> 6;
  const int rowtile = blockIdx.x & 15;
  const int tc      = blockIdx.x >> 4;

  const int rbase = rowtile * 128 + wv * 16;
  const int cellw = rbase >> 10;
  const int rrw   = rbase & 1023;

  short8 aX[8];
  {
    const float* pw = Wih + ((size_t)cellw * G4 + (rrw + lc)) * EE + lg * 8;
    #pragma unroll
    for (int kc = 0; kc < 8; ++kc){
      const f32x4 u = *(const f32x4*)(pw + kc * 32);
      const f32x4 v = *(const f32x4*)(pw + kc * 32 + 4);
      short8 x8;
      #pragma unroll
      for (int e = 0; e < 4; ++e){ x8[e] = (short)f2bf(u[e]); x8[4+e] = (short)f2bf(v[e]); }
      aX[kc] = x8;
    }
  }
  float biasr[4];
  #pragma unroll
  for (int q = 0; q < 4; ++q){
    const int idx = cellw * G4 + rrw + lg * 4 + q;
    biasr[q] = bih[idx] + bhh[idx];
  }

  for (int i = tid; i < TCH * 64; i += TPB){
    const int tl = i >> 6, b = i & 63;
    const int tok = input[b * SS + tc * TCH + tl];
    sTokP[tl][b] = tok; sAsgP[tl][b] = assign[tok];
  }
  __syncthreads();

  const int gkc = tid >> 6, glg = (tid >> 4) & 3, glc = tid & 15;
  short8 xr[4];
  auto GATHERP = [&](int tl){
    #pragma unroll
    for (int ct = 0; ct < 4; ++ct){
      const int tok = sTokP[tl][ct * 16 + glc];
      const float* ep = emb + (size_t)tok * EE + gkc * 32 + glg * 8;
      const f32x4 u = *(const f32x4*)ep;
      const f32x4 v = *(const f32x4*)(ep + 4);
      short8 x8;
      #pragma unroll
      for (int e = 0; e < 4; ++e){ x8[e] = (short)f2bf(u[e]); x8[4+e] = (short)f2bf(v[e]); }
      xr[ct] = x8;
    }
  };
  GATHERP(0);

  for (int tl = 0; tl < TCH; ++tl){
    #pragma unroll
    for (int ct = 0; ct < 4; ++ct)
      *(short8*)&sXp[gkc][glg][ct][glc][0] = xr[ct];
    __syncthreads();
    if (tl + 1 < TCH) GATHERP(tl + 1);

    f32x4 acc[4];
    #pragma unroll
    for (int ct = 0; ct < 4; ++ct){
      acc[ct][0] = biasr[0]; acc[ct][1] = biasr[1];
      acc[ct][2] = biasr[2]; acc[ct][3] = biasr[3];
    }
    #pragma unroll
    for (int kc = 0; kc < 8; ++kc){
      #pragma unroll
      for (int ct = 0; ct < 4; ++ct){
        const short8 bx = *(const short8*)&sXp[kc][lg][ct][lc][0];
        acc[ct] = __builtin_amdgcn_mfma_f32_16x16x32_bf16(aX[kc], bx, acc[ct], 0, 0, 0);
      }
    }
    float* xgt = xg + (size_t)(tc * TCH + tl) * 65536;
    #pragma unroll
    for (int ct = 0; ct < 4; ++ct){
      const int b = ct * 16 + lc;
      if (sAsgP[tl][b] == cellw){
        #pragma unroll
        for (int q = 0; q < 4; ++q)
          xgt[(rrw + lg * 4 + q) * 64 + b] = acc[ct][q];
      }
    }
    __syncthreads();
  }
}

// ---------------- Phase 2: recurrence (batched epoch-in-dword exchange) ----------------
__global__ __launch_bounds__(TPB, 1)
void mlstm_rec_kernel(const int* __restrict__ input, const int* __restrict__ assign,
                      const float* __restrict__ Whh, float* __restrict__ out,
                      char* __restrict__ ws)
{
  __shared__ __align__(16) unsigned short sH[16384];   // 32 KB staged h-hi, swizzled
  __shared__ unsigned int sHout[64][8];                // 2 KB publish bounce {bf16<<16|epoch}
  __shared__ float sC[64][8];                          // 2 KB c-state
  __shared__ int sAsg[3][64];

  const int tid  = threadIdx.x;
  const int lane = tid & 63;
  const int lg   = lane >> 4;
  const int lc   = lane & 15;
  const int wv   = tid >> 6;        // 0..7
  const int cell  = wv & 1;
  const int jhalf = (wv >> 1) & 1;
  const int th    = wv >> 2;        // token half
  const int wg    = blockIdx.x;     // owns j in [wg*8, wg*8+8)

  unsigned int* hbuf = (unsigned int*)(ws + WS_H_OFF);
  const float* xg = (const float*)(ws + WS_XG_OFF);

  // ---- Whh A-frags hi/lo, rows ordered m=(j_sub<<2)|gate (update-ready) ----
  short8 aHiH[8], aLoH[8];
  {
    const float* ph = Whh + ((size_t)cell * G4 + (lc & 3) * HH
                             + wg * 8 + jhalf * 4 + (lc >> 2)) * HH + lg * 8;
    #pragma unroll
    for (int kc = 0; kc < 8; ++kc){
      const f32x4 u = *(const f32x4*)(ph + kc * 32);
      const f32x4 v = *(const f32x4*)(ph + kc * 32 + 4);
      short8 hi, lo;
      #pragma unroll
      for (int e = 0; e < 4; ++e){
        const float w0 = u[e], w1 = v[e];
        const unsigned short h0 = f2bf(w0), h1 = f2bf(w1);
        hi[e] = (short)h0;   lo[e] = (short)f2bf(w0 - bf2f(h0));
        hi[4+e] = (short)h1; lo[4+e] = (short)f2bf(w1 - bf2f(h1));
      }
      aHiH[kc] = hi; aLoH[kc] = lo;
    }
  }

  if (tid < 64){
    const int t0 = input[tid * SS];     sAsg[0][tid] = assign[t0];
    const int t1 = input[tid * SS + 1]; sAsg[1][tid] = assign[t1];
  }

  const int jloc  = jhalf * 4 + lg;
  const int jglob = wg * 8 + jloc;

  float xpre[8];
  auto XPRE = [&](int t){
    const float* p = xg + (size_t)t * 65536 + jglob * 64 + th * 32 + lc;
    #pragma unroll
    for (int ct = 0; ct < 2; ++ct)
      #pragma unroll
      for (int q = 0; q < 4; ++q)
        xpre[ct * 4 + q] = p[q * 16384 + ct * 16];
  };
  XPRE(0);
  __syncthreads();

  // consumer batch-load mapping: thread covers ONE producer slice segment
  const int lslice = tid >> 4;                 // producer slice 0..31
  const int loff   = (tid & 15) * 32;          // dword offset within slice

  for (int t = 0; t < SS; ++t){
    // ---- acquire h(t): sentinel poll + one batched validated load ----
    if (t > 0){
      const unsigned int* bw = hbuf + (size_t)(t & 1) * 16384;
      const unsigned int need = (unsigned int)t;

      if (wv == 0){                            // wave 0: cheap sentinel poll
        const unsigned int* sp = bw + (lane & 31) * 512 + 511;
        int ok;
        do {
          int fr = 1;
          if (lane < NWG){
            unsigned int w;
            asm volatile("global_load_dword %0, %1, off sc0 sc1\n\ts_waitcnt vmcnt(0)"
                         : "=v"(w) : "v"(sp) : "memory");
            fr = ((w & 0xFFFFu) == need);
            if (!fr) __builtin_amdgcn_s_sleep(1);
          }
          ok = (__ballot(fr == 0) == 0ull);
        } while (!ok);
      }
      __syncthreads();

      // batched load of this thread's 32 dwords (one 2KB producer slice segment)
      const unsigned int* base = bw + lslice * 512 + loff;
      uint4v hv[8];
      unsigned bad;
      do {
        #pragma unroll
        for (int i = 0; i < 8; ++i)
          asm volatile("global_load_dwordx4 %0, %1, off sc0 sc1"
                       : "=v"(hv[i]) : "v"(base + i * 4) : "memory");
        asm volatile("s_waitcnt vmcnt(0)" ::: "memory");
        bad = 0;
        #pragma unroll
        for (int i = 0; i < 8; ++i)
          #pragma unroll
          for (int e = 0; e < 4; ++e)
            bad |= (hv[i][e] ^ need);
        bad &= 0xFFFFu;
      } while (bad);
      __builtin_amdgcn_sched_barrier(0);

      // pack hi16 pairs -> 16 shorts; LDS short-index == hbuf dword-index
      const int b0 = (lslice * 512 + loff) * 2;          // byte base in sH
      #pragma unroll
      for (int i = 0; i < 4; ++i){
        uint4v pk;
        pk[0] = (hv[2*i][0]   >> 16) | (hv[2*i][1]   & 0xFFFF0000u);
        pk[1] = (hv[2*i][2]   >> 16) | (hv[2*i][3]   & 0xFFFF0000u);
        pk[2] = (hv[2*i+1][0] >> 16) | (hv[2*i+1][1] & 0xFFFF0000u);
        pk[3] = (hv[2*i+1][2] >> 16) | (hv[2*i+1][3] & 0xFFFF0000u);
        *(uint4v*)((char*)sH + swz(b0 + i * 16)) = pk;
      }
      __syncthreads();
    }

    // ---- acc init from xg; prefetch next step + routing ----
    f32x4 acc[2];
    #pragma unroll
    for (int ct = 0; ct < 2; ++ct)
      #pragma unroll
      for (int q = 0; q < 4; ++q)
        acc[ct][q] = xpre[ct * 4 + q];
    if (t + 1 < SS) XPRE(t + 1);
    if (t + 2 < SS && tid < 64){
      const int tk = input[tid * SS + (t + 2)];
      sAsg[(t + 2) % 3][tid] = assign[tk];
    }

    // ---- h-part MFMAs: (Whi + Wlo)·h_hi, 32 per wave ----
    if (t > 0){
      #pragma unroll
      for (int kch = 0; kch < 8; ++kch){
        const int base = (kch * 4 + lg) * 1024 + th * 512 + lc * 16;
        const short8 hh0 = *(const short8*)((const char*)sH + swz(base));
        const short8 hh1 = *(const short8*)((const char*)sH + swz(base + 256));
        acc[0] = __builtin_amdgcn_mfma_f32_16x16x32_bf16(aHiH[kch], hh0, acc[0], 0, 0, 0);
        acc[1] = __builtin_amdgcn_mfma_f32_16x16x32_bf16(aHiH[kch], hh1, acc[1], 0, 0, 0);
        acc[0] = __builtin_amdgcn_mfma_f32_16x16x32_bf16(aLoH[kch], hh0, acc[0], 0, 0, 0);
        acc[1] = __builtin_amdgcn_mfma_f32_16x16x32_bf16(aLoH[kch], hh1, acc[1], 0, 0, 0);
      }
    }

    // ---- in-register pointwise update: lane has {i,f,g,o} for (jglob, token) ----
    #pragma unroll
    for (int ct = 0; ct < 2; ++ct){
      const int b = th * 32 + ct * 16 + lc;
      const int a = sAsg[t % 3][b];
      if (a == cell){
        const float gi = acc[ct][0], gf = acc[ct][1];
        const float gg = acc[ct][2], go = acc[ct][3];
        const float cold = (t == 0) ? 0.f : sC[b][jloc];
        const float si = 1.f / (1.f + __expf(-gi));
        const float sf = 1.f / (1.f + __expf(-gf));
        const float so = 1.f / (1.f + __expf(-go));
        const float cn = sf * cold + si * tanhf(gg);
        const float hn = so * tanhf(cn);
        if (t < SS - 1){
          sC[b][jloc] = cn;
          sHout[b][jloc] = ((unsigned int)f2bf(hn) << 16) | ((unsigned int)(t + 1) & 0xFFFFu);
        } else {
          out[b * 512 + jglob]       = hn;
          out[b * 512 + 256 + jglob] = cn;
        }
      }
    }

    // ---- publish: coalesced dwordx4 copy-out, fire-and-forget ----
    if (t < SS - 1){
      __syncthreads();
      if (tid < 128){
        const uint4v v = *(const uint4v*)&((const unsigned int*)sHout)[tid * 4];
        unsigned int* dst = hbuf + (size_t)((t & 1) ^ 1) * 16384 + wg * 512 + tid * 4;
        asm volatile("global_store_dwordx4 %0, %1, off sc0 sc1" :: "v"(dst), "v"(v) : "memory");
      }
    }
  }
}

extern "C" void kernel_launch(void* const* d_in, const int* in_sizes, int n_in,
                              void* d_out, int out_size, void* d_ws, size_t ws_size,
                              hipStream_t stream)
{
  const int*   input  = (const int*)  d_in[0];
  const int*   assign = (const int*)  d_in[1];
  const float* emb    = (const float*)d_in[2];
  const float* Wih    = (const float*)d_in[3];
  const float* Whh    = (const float*)d_in[4];
  const float* bih    = (const float*)d_in[5];
  const float* bhh    = (const float*)d_in[6];
  float* out = (float*)d_out;
  char*  ws  = (char*)d_ws;

  zero_ws_kernel<<<64, 256, 0, stream>>>((int*)ws);
  float* xg = (float*)(ws + WS_XG_OFF);
  xproj_kernel<<<256, TPB, 0, stream>>>(input, assign, emb, Wih, bih, bhh, xg);
  mlstm_rec_kernel<<<NWG, TPB, 0, stream>>>(input, assign, Whh, out, ws);
}

// Round 13
// 1854.394 us; speedup vs baseline: 2.0660x; 2.0660x over previous
//
#include <hip/hip_runtime.h>
#include <stdint.h>
#include <stddef.h>

// Routed 2-cell LSTM, B=64, S=512, E=H=256.
// Phase 1 (xproj_kernel): precompute xg[t][g][b] = routed-cell W_ih·x_t + bias.
// Phase 2 (mlstm_rec_kernel, 32 persistent wgs): recurrence with
//   VALIDATION-LOOP-AS-POLL exchange: h value = {bf16<<16|epoch16} dword
//   (aligned dword = single-copy atomic). Producer: LDS bounce -> 128
//   coalesced dwordx4 sc0 sc1 stores, fire-and-forget (NO ack, NO flags).
//   Consumer: per-thread spin { batch-load 8x dwordx4, ONE vmcnt, validate
//   32 epochs } until pass -- on success data is ALREADY in registers (no
//   separate detect+load RTTs). Staging __syncthreads = block-wide AND.
//   Round-9 staging stride (conflict-proven), update-ready MFMA row order.
//   Numerics identical to rounds 8-12.

#define BB   64
#define SS   512
#define EE   256
#define HH   256
#define G4   1024
#define NWG  32
#define TPB  512
#define TCH  32

typedef __attribute__((ext_vector_type(8))) short short8;
typedef __attribute__((ext_vector_type(4))) float f32x4;
typedef __attribute__((ext_vector_type(4))) unsigned int uint4v;
typedef __attribute__((ext_vector_type(2))) unsigned int uint2v;

__device__ __forceinline__ unsigned short f2bf(float f){
  union { float f; unsigned u; } v; v.f = f;
  return (unsigned short)((v.u + 0x7fffu + ((v.u >> 16) & 1u)) >> 16);
}
__device__ __forceinline__ float bf2f(unsigned short s){
  union { float f; unsigned u; } v; v.u = ((unsigned)s) << 16;
  return v.f;
}
__device__ __forceinline__ int swz(int byte){ return byte ^ (((byte >> 10) & 3) << 6); }

// ws layout (bytes):
// [1024, +131072)      : h dwords {bf16<<16|epoch}, 2 parities x 16384 dwords
//                        dword index within parity: wg*512 + b*8 + jloc
// [132096, +134217728) : xg[t=512][g=1024][b=64] fp32 (routed-cell gates)
#define WS_H_OFF  1024
#define WS_XG_OFF (1024 + 131072)

__global__ void zero_ws_kernel(int* ws){
  // sc0 sc1 stores so zeros land at the coherence point (no stale IF lines
  // across graph replays).
  const int n = (WS_H_OFF + 131072) / 4;
  for (int i = blockIdx.x * blockDim.x + threadIdx.x; i < n; i += gridDim.x * blockDim.x){
    int* p = ws + i;
    const int z = 0;
    asm volatile("global_store_dword %0, %1, off sc0 sc1" :: "v"(p), "v"(z) : "memory");
  }
}

// ---------------- Phase 1: x-projection GEMM ----------------
__global__ __launch_bounds__(TPB, 1)
void xproj_kernel(const int* __restrict__ input, const int* __restrict__ assign,
                  const float* __restrict__ emb, const float* __restrict__ Wih,
                  const float* __restrict__ bih, const float* __restrict__ bhh,
                  float* __restrict__ xg)
{
  __shared__ __align__(16) unsigned short sXp[8][4][4][16][8];
  __shared__ int sTokP[TCH][64];
  __shared__ int sAsgP[TCH][64];

  const int tid  = threadIdx.x;
  const int lane = tid & 63;
  const int lg   = lane >> 4;
  const int lc   = lane & 15;
  const int wv   = tid >> 6;
  const int rowtile = blockIdx.x & 15;
  const int tc      = blockIdx.x >> 4;

  const int rbase = rowtile * 128 + wv * 16;
  const int cellw = rbase >> 10;
  const int rrw   = rbase & 1023;

  short8 aX[8];
  {
    const float* pw = Wih + ((size_t)cellw * G4 + (rrw + lc)) * EE + lg * 8;
    #pragma unroll
    for (int kc = 0; kc < 8; ++kc){
      const f32x4 u = *(const f32x4*)(pw + kc * 32);
      const f32x4 v = *(const f32x4*)(pw + kc * 32 + 4);
      short8 x8;
      #pragma unroll
      for (int e = 0; e < 4; ++e){ x8[e] = (short)f2bf(u[e]); x8[4+e] = (short)f2bf(v[e]); }
      aX[kc] = x8;
    }
  }
  float biasr[4];
  #pragma unroll
  for (int q = 0; q < 4; ++q){
    const int idx = cellw * G4 + rrw + lg * 4 + q;
    biasr[q] = bih[idx] + bhh[idx];
  }

  for (int i = tid; i < TCH * 64; i += TPB){
    const int tl = i >> 6, b = i & 63;
    const int tok = input[b * SS + tc * TCH + tl];
    sTokP[tl][b] = tok; sAsgP[tl][b] = assign[tok];
  }
  __syncthreads();

  const int gkc = tid >> 6, glg = (tid >> 4) & 3, glc = tid & 15;
  short8 xr[4];
  auto GATHERP = [&](int tl){
    #pragma unroll
    for (int ct = 0; ct < 4; ++ct){
      const int tok = sTokP[tl][ct * 16 + glc];
      const float* ep = emb + (size_t)tok * EE + gkc * 32 + glg * 8;
      const f32x4 u = *(const f32x4*)ep;
      const f32x4 v = *(const f32x4*)(ep + 4);
      short8 x8;
      #pragma unroll
      for (int e = 0; e < 4; ++e){ x8[e] = (short)f2bf(u[e]); x8[4+e] = (short)f2bf(v[e]); }
      xr[ct] = x8;
    }
  };
  GATHERP(0);

  for (int tl = 0; tl < TCH; ++tl){
    #pragma unroll
    for (int ct = 0; ct < 4; ++ct)
      *(short8*)&sXp[gkc][glg][ct][glc][0] = xr[ct];
    __syncthreads();
    if (tl + 1 < TCH) GATHERP(tl + 1);

    f32x4 acc[4];
    #pragma unroll
    for (int ct = 0; ct < 4; ++ct){
      acc[ct][0] = biasr[0]; acc[ct][1] = biasr[1];
      acc[ct][2] = biasr[2]; acc[ct][3] = biasr[3];
    }
    #pragma unroll
    for (int kc = 0; kc < 8; ++kc){
      #pragma unroll
      for (int ct = 0; ct < 4; ++ct){
        const short8 bx = *(const short8*)&sXp[kc][lg][ct][lc][0];
        acc[ct] = __builtin_amdgcn_mfma_f32_16x16x32_bf16(aX[kc], bx, acc[ct], 0, 0, 0);
      }
    }
    float* xgt = xg + (size_t)(tc * TCH + tl) * 65536;
    #pragma unroll
    for (int ct = 0; ct < 4; ++ct){
      const int b = ct * 16 + lc;
      if (sAsgP[tl][b] == cellw){
        #pragma unroll
        for (int q = 0; q < 4; ++q)
          xgt[(rrw + lg * 4 + q) * 64 + b] = acc[ct][q];
      }
    }
    __syncthreads();
  }
}

// ---------------- Phase 2: recurrence (validation-loop-as-poll) ----------------
__global__ __launch_bounds__(TPB, 1)
void mlstm_rec_kernel(const int* __restrict__ input, const int* __restrict__ assign,
                      const float* __restrict__ Whh, float* __restrict__ out,
                      char* __restrict__ ws)
{
  __shared__ __align__(16) unsigned short sH[16384];   // 32 KB staged h-hi, swizzled
  __shared__ unsigned int sHout[64][8];                // 2 KB publish bounce {bf16<<16|epoch}
  __shared__ float sC[64][8];                          // 2 KB c-state
  __shared__ int sAsg[3][64];

  const int tid  = threadIdx.x;
  const int lane = tid & 63;
  const int lg   = lane >> 4;
  const int lc   = lane & 15;
  const int wv   = tid >> 6;        // 0..7
  const int cell  = wv & 1;
  const int jhalf = (wv >> 1) & 1;
  const int th    = wv >> 2;        // token half
  const int wg    = blockIdx.x;     // owns j in [wg*8, wg*8+8)

  unsigned int* hbuf = (unsigned int*)(ws + WS_H_OFF);
  const float* xg = (const float*)(ws + WS_XG_OFF);

  // ---- Whh A-frags hi/lo, rows ordered m=(j_sub<<2)|gate (update-ready) ----
  short8 aHiH[8], aLoH[8];
  {
    const float* ph = Whh + ((size_t)cell * G4 + (lc & 3) * HH
                             + wg * 8 + jhalf * 4 + (lc >> 2)) * HH + lg * 8;
    #pragma unroll
    for (int kc = 0; kc < 8; ++kc){
      const f32x4 u = *(const f32x4*)(ph + kc * 32);
      const f32x4 v = *(const f32x4*)(ph + kc * 32 + 4);
      short8 hi, lo;
      #pragma unroll
      for (int e = 0; e < 4; ++e){
        const float w0 = u[e], w1 = v[e];
        const unsigned short h0 = f2bf(w0), h1 = f2bf(w1);
        hi[e] = (short)h0;   lo[e] = (short)f2bf(w0 - bf2f(h0));
        hi[4+e] = (short)h1; lo[4+e] = (short)f2bf(w1 - bf2f(h1));
      }
      aHiH[kc] = hi; aLoH[kc] = lo;
    }
  }

  if (tid < 64){
    const int t0 = input[tid * SS];     sAsg[0][tid] = assign[t0];
    const int t1 = input[tid * SS + 1]; sAsg[1][tid] = assign[t1];
  }

  const int jloc  = jhalf * 4 + lg;
  const int jglob = wg * 8 + jloc;

  float xpre[8];
  auto XPRE = [&](int t){
    const float* p = xg + (size_t)t * 65536 + jglob * 64 + th * 32 + lc;
    #pragma unroll
    for (int ct = 0; ct < 2; ++ct)
      #pragma unroll
      for (int q = 0; q < 4; ++q)
        xpre[ct * 4 + q] = p[q * 16384 + ct * 16];
  };
  XPRE(0);
  __syncthreads();

  for (int t = 0; t < SS; ++t){
    // ---- acc init from xg (independent of h); prefetch next step + routing ----
    f32x4 acc[2];
    #pragma unroll
    for (int ct = 0; ct < 2; ++ct)
      #pragma unroll
      for (int q = 0; q < 4; ++q)
        acc[ct][q] = xpre[ct * 4 + q];
    if (t + 1 < SS) XPRE(t + 1);
    if (t + 2 < SS && tid < 64){
      const int tk = input[tid * SS + (t + 2)];
      sAsg[(t + 2) % 3][tid] = assign[tk];
    }

    // ---- acquire h(t): per-thread validation spin (poll == load) ----
    if (t > 0){
      const unsigned int* bw = hbuf + (size_t)(t & 1) * 16384;
      const unsigned int need = (unsigned int)t;

      uint4v hv[8];
      unsigned bad;
      do {
        #pragma unroll
        for (int i = 0; i < 8; ++i){
          const unsigned int* p = bw + (i * 512 + tid) * 4;
          asm volatile("global_load_dwordx4 %0, %1, off sc0 sc1"
                       : "=v"(hv[i]) : "v"(p) : "memory");
        }
        asm volatile("s_waitcnt vmcnt(0)" ::: "memory");
        bad = 0;
        #pragma unroll
        for (int i = 0; i < 8; ++i)
          #pragma unroll
          for (int e = 0; e < 4; ++e)
            bad |= (hv[i][e] ^ need);
        bad &= 0xFFFFu;
        if (bad) __builtin_amdgcn_s_sleep(1);
      } while (bad);
      __builtin_amdgcn_sched_barrier(0);

      // pack hi16 pairs -> 4 shorts (8B) per chunk; LDS short-index == dword-index
      #pragma unroll
      for (int i = 0; i < 8; ++i){
        uint2v pk;
        pk[0] = (hv[i][0] >> 16) | (hv[i][1] & 0xFFFF0000u);
        pk[1] = (hv[i][2] >> 16) | (hv[i][3] & 0xFFFF0000u);
        *(uint2v*)((char*)sH + swz((i * 512 + tid) * 8)) = pk;
      }
      __syncthreads();
    }

    // ---- h-part MFMAs: (Whi + Wlo)·h_hi, 32 per wave ----
    if (t > 0){
      #pragma unroll
      for (int kch = 0; kch < 8; ++kch){
        const int base = (kch * 4 + lg) * 1024 + th * 512 + lc * 16;
        const short8 hh0 = *(const short8*)((const char*)sH + swz(base));
        const short8 hh1 = *(const short8*)((const char*)sH + swz(base + 256));
        acc[0] = __builtin_amdgcn_mfma_f32_16x16x32_bf16(aHiH[kch], hh0, acc[0], 0, 0, 0);
        acc[1] = __builtin_amdgcn_mfma_f32_16x16x32_bf16(aHiH[kch], hh1, acc[1], 0, 0, 0);
        acc[0] = __builtin_amdgcn_mfma_f32_16x16x32_bf16(aLoH[kch], hh0, acc[0], 0, 0, 0);
        acc[1] = __builtin_amdgcn_mfma_f32_16x16x32_bf16(aLoH[kch], hh1, acc[1], 0, 0, 0);
      }
    }

    // ---- in-register pointwise update: lane has {i,f,g,o} for (jglob, token) ----
    #pragma unroll
    for (int ct = 0; ct < 2; ++ct){
      const int b = th * 32 + ct * 16 + lc;
      const int a = sAsg[t % 3][b];
      if (a == cell){
        const float gi = acc[ct][0], gf = acc[ct][1];
        const float gg = acc[ct][2], go = acc[ct][3];
        const float cold = (t == 0) ? 0.f : sC[b][jloc];
        const float si = 1.f / (1.f + __expf(-gi));
        const float sf = 1.f / (1.f + __expf(-gf));
        const float so = 1.f / (1.f + __expf(-go));
        const float cn = sf * cold + si * tanhf(gg);
        const float hn = so * tanhf(cn);
        if (t < SS - 1){
          sC[b][jloc] = cn;
          sHout[b][jloc] = ((unsigned int)f2bf(hn) << 16) | ((unsigned int)(t + 1) & 0xFFFFu);
        } else {
          out[b * 512 + jglob]       = hn;
          out[b * 512 + 256 + jglob] = cn;
        }
      }
    }

    // ---- publish: coalesced dwordx4 copy-out, fire-and-forget (no ack, no flag) ----
    if (t < SS - 1){
      __syncthreads();
      if (tid < 128){
        const uint4v v = *(const uint4v*)&((const unsigned int*)sHout)[tid * 4];
        unsigned int* dst = hbuf + (size_t)((t & 1) ^ 1) * 16384 + wg * 512 + tid * 4;
        asm volatile("global_store_dwordx4 %0, %1, off sc0 sc1" :: "v"(dst), "v"(v) : "memory");
      }
    }
  }
}

extern "C" void kernel_launch(void* const* d_in, const int* in_sizes, int n_in,
                              void* d_out, int out_size, void* d_ws, size_t ws_size,
                              hipStream_t stream)
{
  const int*   input  = (const int*)  d_in[0];
  const int*   assign = (const int*)  d_in[1];
  const float* emb    = (const float*)d_in[2];
  const float* Wih    = (const float*)d_in[3];
  const float* Whh    = (const float*)d_in[4];
  const float* bih    = (const float*)d_in[5];
  const float* bhh    = (const float*)d_in[6];
  float* out = (float*)d_out;
  char*  ws  = (char*)d_ws;

  zero_ws_kernel<<<64, 256, 0, stream>>>((int*)ws);
  float* xg = (float*)(ws + WS_XG_OFF);
  xproj_kernel<<<256, TPB, 0, stream>>>(input, assign, emb, Wih, bih, bhh, xg);
  mlstm_rec_kernel<<<NWG, TPB, 0, stream>>>(input, assign, Whh, out, ws);
}

// Round 14
// 1198.720 us; speedup vs baseline: 3.1961x; 1.5470x over previous
//
#include <hip/hip_runtime.h>
#include <stdint.h>
#include <stddef.h>

// Routed 2-cell LSTM, B=64, S=512, E=H=256.
// Phase 1 (xproj_kernel, 512 blocks): xg[t][g][b] = routed-cell W_ih·x_t + bias.
// Phase 2 (mlstm_rec_kernel, 64 persistent wgs = 32 j-slices x 2 TOKEN-HALF
//   POOLS): tokens are independent recurrences, so each wg syncs/exchanges
//   only within its 32-token pool -> spin payload 32KB (half), 16 MFMAs/wave.
//   Exchange = validation-loop-as-poll (round 13): h = {bf16<<16|epoch16}
//   dword, consumer spin {4x dwordx4, one vmcnt, validate 16 epochs} until
//   pass (data already in regs). Publish = DIRECT per-lane dword stores
//   (no LDS bounce, no publish barrier) - safe by validation-induction.
//   Update-ready MFMA row ordering. Numerics bit-identical to round 13.

#define BB   64
#define SS   512
#define EE   256
#define HH   256
#define G4   1024
#define NWG  64
#define TPB  512
#define TCH  16

typedef __attribute__((ext_vector_type(8))) short short8;
typedef __attribute__((ext_vector_type(4))) float f32x4;
typedef __attribute__((ext_vector_type(4))) unsigned int uint4v;
typedef __attribute__((ext_vector_type(2))) unsigned int uint2v;

__device__ __forceinline__ unsigned short f2bf(float f){
  union { float f; unsigned u; } v; v.f = f;
  return (unsigned short)((v.u + 0x7fffu + ((v.u >> 16) & 1u)) >> 16);
}
__device__ __forceinline__ float bf2f(unsigned short s){
  union { float f; unsigned u; } v; v.u = ((unsigned)s) << 16;
  return v.f;
}
// slice stride is now 512B -> XOR byte bits 9-10 (lg) into bits 5-6
__device__ __forceinline__ int swz2(int byte){ return byte ^ (((byte >> 9) & 3) << 5); }

// ws layout (bytes):
// [1024, +131072)      : h dwords {bf16<<16|epoch}, 2 parities x 16384 dwords;
//                        within parity: thG*8192 + jset*256 + b_local*8 + jloc
// [132096, +134217728) : xg[t=512][g=1024][b=64] fp32 (routed-cell gates)
#define WS_H_OFF  1024
#define WS_XG_OFF (1024 + 131072)

__global__ void zero_ws_kernel(int* ws){
  const int n = (WS_H_OFF + 131072) / 4;
  for (int i = blockIdx.x * blockDim.x + threadIdx.x; i < n; i += gridDim.x * blockDim.x){
    int* p = ws + i;
    const int z = 0;
    asm volatile("global_store_dword %0, %1, off sc0 sc1" :: "v"(p), "v"(z) : "memory");
  }
}

// ---------------- Phase 1: x-projection GEMM (512 blocks) ----------------
__global__ __launch_bounds__(TPB, 1)
void xproj_kernel(const int* __restrict__ input, const int* __restrict__ assign,
                  const float* __restrict__ emb, const float* __restrict__ Wih,
                  const float* __restrict__ bih, const float* __restrict__ bhh,
                  float* __restrict__ xg)
{
  __shared__ __align__(16) unsigned short sXp[8][4][4][16][8];
  __shared__ int sTokP[TCH][64];
  __shared__ int sAsgP[TCH][64];

  const int tid  = threadIdx.x;
  const int lane = tid & 63;
  const int lg   = lane >> 4;
  const int lc   = lane & 15;
  const int wv   = tid >> 6;
  const int rowtile = blockIdx.x & 15;   // 16 tiles of 128 gate rows
  const int tc      = blockIdx.x >> 4;   // 32 chunks of TCH steps

  const int rbase = rowtile * 128 + wv * 16;
  const int cellw = rbase >> 10;
  const int rrw   = rbase & 1023;

  short8 aX[8];
  {
    const float* pw = Wih + ((size_t)cellw * G4 + (rrw + lc)) * EE + lg * 8;
    #pragma unroll
    for (int kc = 0; kc < 8; ++kc){
      const f32x4 u = *(const f32x4*)(pw + kc * 32);
      const f32x4 v = *(const f32x4*)(pw + kc * 32 + 4);
      short8 x8;
      #pragma unroll
      for (int e = 0; e < 4; ++e){ x8[e] = (short)f2bf(u[e]); x8[4+e] = (short)f2bf(v[e]); }
      aX[kc] = x8;
    }
  }
  float biasr[4];
  #pragma unroll
  for (int q = 0; q < 4; ++q){
    const int idx = cellw * G4 + rrw + lg * 4 + q;
    biasr[q] = bih[idx] + bhh[idx];
  }

  for (int i = tid; i < TCH * 64; i += TPB){
    const int tl = i >> 6, b = i & 63;
    const int tok = input[b * SS + tc * TCH + tl];
    sTokP[tl][b] = tok; sAsgP[tl][b] = assign[tok];
  }
  __syncthreads();

  const int gkc = tid >> 6, glg = (tid >> 4) & 3, glc = tid & 15;
  short8 xr[4];
  auto GATHERP = [&](int tl){
    #pragma unroll
    for (int ct = 0; ct < 4; ++ct){
      const int tok = sTokP[tl][ct * 16 + glc];
      const float* ep = emb + (size_t)tok * EE + gkc * 32 + glg * 8;
      const f32x4 u = *(const f32x4*)ep;
      const f32x4 v = *(const f32x4*)(ep + 4);
      short8 x8;
      #pragma unroll
      for (int e = 0; e < 4; ++e){ x8[e] = (short)f2bf(u[e]); x8[4+e] = (short)f2bf(v[e]); }
      xr[ct] = x8;
    }
  };
  GATHERP(0);

  for (int tl = 0; tl < TCH; ++tl){
    #pragma unroll
    for (int ct = 0; ct < 4; ++ct)
      *(short8*)&sXp[gkc][glg][ct][glc][0] = xr[ct];
    __syncthreads();
    if (tl + 1 < TCH) GATHERP(tl + 1);

    f32x4 acc[4];
    #pragma unroll
    for (int ct = 0; ct < 4; ++ct){
      acc[ct][0] = biasr[0]; acc[ct][1] = biasr[1];
      acc[ct][2] = biasr[2]; acc[ct][3] = biasr[3];
    }
    #pragma unroll
    for (int kc = 0; kc < 8; ++kc){
      #pragma unroll
      for (int ct = 0; ct < 4; ++ct){
        const short8 bx = *(const short8*)&sXp[kc][lg][ct][lc][0];
        acc[ct] = __builtin_amdgcn_mfma_f32_16x16x32_bf16(aX[kc], bx, acc[ct], 0, 0, 0);
      }
    }
    float* xgt = xg + (size_t)(tc * TCH + tl) * 65536;
    #pragma unroll
    for (int ct = 0; ct < 4; ++ct){
      const int b = ct * 16 + lc;
      if (sAsgP[tl][b] == cellw){
        #pragma unroll
        for (int q = 0; q < 4; ++q)
          xgt[(rrw + lg * 4 + q) * 64 + b] = acc[ct][q];
      }
    }
    __syncthreads();
  }
}

// ---------------- Phase 2: recurrence (token-half pools) ----------------
__global__ __launch_bounds__(TPB, 1)
void mlstm_rec_kernel(const int* __restrict__ input, const int* __restrict__ assign,
                      const float* __restrict__ Whh, float* __restrict__ out,
                      char* __restrict__ ws)
{
  __shared__ __align__(16) unsigned short sH[8192];    // 16 KB staged h-hi (pool), swizzled
  __shared__ float sC[32][8];                          // 1 KB c-state (pool-local)
  __shared__ int sAsg[3][64];

  const int tid  = threadIdx.x;
  const int lane = tid & 63;
  const int lg   = lane >> 4;
  const int lc   = lane & 15;
  const int wv   = tid >> 6;        // 0..7
  const int cell  = wv & 1;
  const int jhalf = (wv >> 1) & 1;
  const int ct    = wv >> 2;        // 16-token tile within pool
  const int wg    = blockIdx.x;     // 0..63
  const int jset  = wg & 31;        // owns j in [jset*8, jset*8+8)
  const int thG   = wg >> 5;        // token-half pool 0/1

  unsigned int* hbuf = (unsigned int*)(ws + WS_H_OFF);
  const float* xg = (const float*)(ws + WS_XG_OFF);

  // ---- Whh A-frags hi/lo, rows ordered m=(j_sub<<2)|gate (update-ready) ----
  short8 aHiH[8], aLoH[8];
  {
    const float* ph = Whh + ((size_t)cell * G4 + (lc & 3) * HH
                             + jset * 8 + jhalf * 4 + (lc >> 2)) * HH + lg * 8;
    #pragma unroll
    for (int kc = 0; kc < 8; ++kc){
      const f32x4 u = *(const f32x4*)(ph + kc * 32);
      const f32x4 v = *(const f32x4*)(ph + kc * 32 + 4);
      short8 hi, lo;
      #pragma unroll
      for (int e = 0; e < 4; ++e){
        const float w0 = u[e], w1 = v[e];
        const unsigned short h0 = f2bf(w0), h1 = f2bf(w1);
        hi[e] = (short)h0;   lo[e] = (short)f2bf(w0 - bf2f(h0));
        hi[4+e] = (short)h1; lo[4+e] = (short)f2bf(w1 - bf2f(h1));
      }
      aHiH[kc] = hi; aLoH[kc] = lo;
    }
  }

  if (tid < 64){
    const int t0 = input[tid * SS];     sAsg[0][tid] = assign[t0];
    const int t1 = input[tid * SS + 1]; sAsg[1][tid] = assign[t1];
  }

  const int jloc   = jhalf * 4 + lg;      // 0..7
  const int jglob  = jset * 8 + jloc;
  const int b_loc  = ct * 16 + lc;        // 0..31 within pool
  const int b_glob = thG * 32 + b_loc;

  float xpre[4];
  auto XPRE = [&](int t){
    const float* p = xg + (size_t)t * 65536 + jglob * 64 + b_glob;
    #pragma unroll
    for (int q = 0; q < 4; ++q)
      xpre[q] = p[q * 16384];
  };
  XPRE(0);
  __syncthreads();

  for (int t = 0; t < SS; ++t){
    // ---- acc init from xg; prefetch next step + routing ----
    f32x4 acc;
    #pragma unroll
    for (int q = 0; q < 4; ++q) acc[q] = xpre[q];
    if (t + 1 < SS) XPRE(t + 1);
    if (t + 2 < SS && tid < 64){
      const int tk = input[tid * SS + (t + 2)];
      sAsg[(t + 2) % 3][tid] = assign[tk];
    }

    // ---- acquire pool h(t): per-thread validation spin (poll == load) ----
    if (t > 0){
      const unsigned int* bw = hbuf + (size_t)(t & 1) * 16384 + thG * 8192;
      const unsigned int need = (unsigned int)t;

      uint4v hv[4];
      unsigned bad;
      do {
        #pragma unroll
        for (int i = 0; i < 4; ++i){
          const unsigned int* p = bw + (i * 512 + tid) * 4;
          asm volatile("global_load_dwordx4 %0, %1, off sc0 sc1"
                       : "=v"(hv[i]) : "v"(p) : "memory");
        }
        asm volatile("s_waitcnt vmcnt(0)" ::: "memory");
        bad = 0;
        #pragma unroll
        for (int i = 0; i < 4; ++i)
          #pragma unroll
          for (int e = 0; e < 4; ++e)
            bad |= (hv[i][e] ^ need);
        bad &= 0xFFFFu;
        if (bad) __builtin_amdgcn_s_sleep(1);
      } while (bad);
      __builtin_amdgcn_sched_barrier(0);

      // pack hi16 pairs; LDS short-index == pool dword-index
      #pragma unroll
      for (int i = 0; i < 4; ++i){
        uint2v pk;
        pk[0] = (hv[i][0] >> 16) | (hv[i][1] & 0xFFFF0000u);
        pk[1] = (hv[i][2] >> 16) | (hv[i][3] & 0xFFFF0000u);
        *(uint2v*)((char*)sH + swz2((i * 512 + tid) * 8)) = pk;
      }
      __syncthreads();
    }

    // ---- h-part MFMAs: (Whi + Wlo)·h_hi, 16 per wave ----
    if (t > 0){
      #pragma unroll
      for (int kch = 0; kch < 8; ++kch){
        const int base = (kch * 4 + lg) * 512 + ct * 256 + lc * 16;
        const short8 hh = *(const short8*)((const char*)sH + swz2(base));
        acc = __builtin_amdgcn_mfma_f32_16x16x32_bf16(aHiH[kch], hh, acc, 0, 0, 0);
        acc = __builtin_amdgcn_mfma_f32_16x16x32_bf16(aLoH[kch], hh, acc, 0, 0, 0);
      }
    }

    // ---- in-register update + DIRECT per-lane publish (no bounce, no barrier) ----
    {
      const int a = sAsg[t % 3][b_glob];
      if (a == cell){
        const float gi = acc[0], gf = acc[1], gg = acc[2], go = acc[3];
        const float cold = (t == 0) ? 0.f : sC[b_loc][jloc];
        const float si = 1.f / (1.f + __expf(-gi));
        const float sf = 1.f / (1.f + __expf(-gf));
        const float so = 1.f / (1.f + __expf(-go));
        const float cn = sf * cold + si * tanhf(gg);
        const float hn = so * tanhf(cn);
        if (t < SS - 1){
          sC[b_loc][jloc] = cn;
          const unsigned word = ((unsigned)f2bf(hn) << 16) | ((unsigned)(t + 1) & 0xFFFFu);
          unsigned int* dst = hbuf + (size_t)((t & 1) ^ 1) * 16384 + thG * 8192
                            + jset * 256 + b_loc * 8 + jloc;
          asm volatile("global_store_dword %0, %1, off sc0 sc1" :: "v"(dst), "v"(word) : "memory");
        } else {
          out[b_glob * 512 + jglob]       = hn;
          out[b_glob * 512 + 256 + jglob] = cn;
        }
      }
    }
    // no publish barrier: next step's validation (needs own wg's stores) is the sync.
  }
}

extern "C" void kernel_launch(void* const* d_in, const int* in_sizes, int n_in,
                              void* d_out, int out_size, void* d_ws, size_t ws_size,
                              hipStream_t stream)
{
  const int*   input  = (const int*)  d_in[0];
  const int*   assign = (const int*)  d_in[1];
  const float* emb    = (const float*)d_in[2];
  const float* Wih    = (const float*)d_in[3];
  const float* Whh    = (const float*)d_in[4];
  const float* bih    = (const float*)d_in[5];
  const float* bhh    = (const float*)d_in[6];
  float* out = (float*)d_out;
  char*  ws  = (char*)d_ws;

  zero_ws_kernel<<<64, 256, 0, stream>>>((int*)ws);
  float* xg = (float*)(ws + WS_XG_OFF);
  xproj_kernel<<<512, TPB, 0, stream>>>(input, assign, emb, Wih, bih, bhh, xg);
  mlstm_rec_kernel<<<NWG, TPB, 0, stream>>>(input, assign, Whh, out, ws);
}

// Round 15
// 1112.246 us; speedup vs baseline: 3.4446x; 1.0777x over previous
//
#include <hip/hip_runtime.h>
#include <stdint.h>
#include <stddef.h>

// Routed 2-cell LSTM, B=64, S=512, E=H=256.
// Phase 1 (xproj_kernel, 512 blocks): xg[t][g][b] = routed-cell W_ih·x_t + bias.
// Phase 2 (mlstm_rec_kernel, 64 wgs = 16 j-slices x 4 TOKEN POOLS of 16):
//   each pool is a self-contained 16-wg recurrence: spin payload 16KB,
//   16 producers/pool. Exchange = validation-loop-as-poll (round 13):
//   h = {bf16<<16|epoch16} dword; consumer spin {2x dwordx4, one vmcnt,
//   validate 8 epochs} until pass (data already in regs). Direct per-lane
//   publish (no bounce, no barrier). Update-ready MFMA row ordering.
//   Numerics bit-identical to rounds 13/14.

#define BB   64
#define SS   512
#define EE   256
#define HH   256
#define G4   1024
#define NWG  64
#define TPB  512
#define TCH  16

typedef __attribute__((ext_vector_type(8))) short short8;
typedef __attribute__((ext_vector_type(4))) float f32x4;
typedef __attribute__((ext_vector_type(4))) unsigned int uint4v;

__device__ __forceinline__ unsigned short f2bf(float f){
  union { float f; unsigned u; } v; v.f = f;
  return (unsigned short)((v.u + 0x7fffu + ((v.u >> 16) & 1u)) >> 16);
}
__device__ __forceinline__ float bf2f(unsigned short s){
  union { float f; unsigned u; } v; v.u = ((unsigned)s) << 16;
  return v.f;
}
// 16B-granule swizzle for the [js][b][jl] pool layout: XOR byte bits 8:7
// (b>>2) into bits 5:4 -> <=2-way banks on staging write and frag read.
__device__ __forceinline__ int swz3(int byte){ return byte ^ (((byte >> 7) & 3) << 4); }

// ws layout (bytes):
// [1024, +131072)      : h dwords {bf16<<16|epoch}, 2 parities x 16384 dwords;
//                        within parity: pool*4096 + js*256 + b_loc*16 + jl
// [132096, +134217728) : xg[t=512][g=1024][b=64] fp32 (routed-cell gates)
#define WS_H_OFF  1024
#define WS_XG_OFF (1024 + 131072)

__global__ void zero_ws_kernel(int* ws){
  const int n = (WS_H_OFF + 131072) / 4;
  for (int i = blockIdx.x * blockDim.x + threadIdx.x; i < n; i += gridDim.x * blockDim.x){
    int* p = ws + i;
    const int z = 0;
    asm volatile("global_store_dword %0, %1, off sc0 sc1" :: "v"(p), "v"(z) : "memory");
  }
}

// ---------------- Phase 1: x-projection GEMM (512 blocks) ----------------
__global__ __launch_bounds__(TPB, 1)
void xproj_kernel(const int* __restrict__ input, const int* __restrict__ assign,
                  const float* __restrict__ emb, const float* __restrict__ Wih,
                  const float* __restrict__ bih, const float* __restrict__ bhh,
                  float* __restrict__ xg)
{
  __shared__ __align__(16) unsigned short sXp[8][4][4][16][8];
  __shared__ int sTokP[TCH][64];
  __shared__ int sAsgP[TCH][64];

  const int tid  = threadIdx.x;
  const int lane = tid & 63;
  const int lg   = lane >> 4;
  const int lc   = lane & 15;
  const int wv   = tid >> 6;
  const int rowtile = blockIdx.x & 15;   // 16 tiles of 128 gate rows
  const int tc      = blockIdx.x >> 4;   // 32 chunks of TCH steps

  const int rbase = rowtile * 128 + wv * 16;
  const int cellw = rbase >> 10;
  const int rrw   = rbase & 1023;

  short8 aX[8];
  {
    const float* pw = Wih + ((size_t)cellw * G4 + (rrw + lc)) * EE + lg * 8;
    #pragma unroll
    for (int kc = 0; kc < 8; ++kc){
      const f32x4 u = *(const f32x4*)(pw + kc * 32);
      const f32x4 v = *(const f32x4*)(pw + kc * 32 + 4);
      short8 x8;
      #pragma unroll
      for (int e = 0; e < 4; ++e){ x8[e] = (short)f2bf(u[e]); x8[4+e] = (short)f2bf(v[e]); }
      aX[kc] = x8;
    }
  }
  float biasr[4];
  #pragma unroll
  for (int q = 0; q < 4; ++q){
    const int idx = cellw * G4 + rrw + lg * 4 + q;
    biasr[q] = bih[idx] + bhh[idx];
  }

  for (int i = tid; i < TCH * 64; i += TPB){
    const int tl = i >> 6, b = i & 63;
    const int tok = input[b * SS + tc * TCH + tl];
    sTokP[tl][b] = tok; sAsgP[tl][b] = assign[tok];
  }
  __syncthreads();

  const int gkc = tid >> 6, glg = (tid >> 4) & 3, glc = tid & 15;
  short8 xr[4];
  auto GATHERP = [&](int tl){
    #pragma unroll
    for (int ct = 0; ct < 4; ++ct){
      const int tok = sTokP[tl][ct * 16 + glc];
      const float* ep = emb + (size_t)tok * EE + gkc * 32 + glg * 8;
      const f32x4 u = *(const f32x4*)ep;
      const f32x4 v = *(const f32x4*)(ep + 4);
      short8 x8;
      #pragma unroll
      for (int e = 0; e < 4; ++e){ x8[e] = (short)f2bf(u[e]); x8[4+e] = (short)f2bf(v[e]); }
      xr[ct] = x8;
    }
  };
  GATHERP(0);

  for (int tl = 0; tl < TCH; ++tl){
    #pragma unroll
    for (int ct = 0; ct < 4; ++ct)
      *(short8*)&sXp[gkc][glg][ct][glc][0] = xr[ct];
    __syncthreads();
    if (tl + 1 < TCH) GATHERP(tl + 1);

    f32x4 acc[4];
    #pragma unroll
    for (int ct = 0; ct < 4; ++ct){
      acc[ct][0] = biasr[0]; acc[ct][1] = biasr[1];
      acc[ct][2] = biasr[2]; acc[ct][3] = biasr[3];
    }
    #pragma unroll
    for (int kc = 0; kc < 8; ++kc){
      #pragma unroll
      for (int ct = 0; ct < 4; ++ct){
        const short8 bx = *(const short8*)&sXp[kc][lg][ct][lc][0];
        acc[ct] = __builtin_amdgcn_mfma_f32_16x16x32_bf16(aX[kc], bx, acc[ct], 0, 0, 0);
      }
    }
    float* xgt = xg + (size_t)(tc * TCH + tl) * 65536;
    #pragma unroll
    for (int ct = 0; ct < 4; ++ct){
      const int b = ct * 16 + lc;
      if (sAsgP[tl][b] == cellw){
        #pragma unroll
        for (int q = 0; q < 4; ++q)
          xgt[(rrw + lg * 4 + q) * 64 + b] = acc[ct][q];
      }
    }
    __syncthreads();
  }
}

// ---------------- Phase 2: recurrence (16 j-slices x 4 pools) ----------------
__global__ __launch_bounds__(TPB, 1)
void mlstm_rec_kernel(const int* __restrict__ input, const int* __restrict__ assign,
                      const float* __restrict__ Whh, float* __restrict__ out,
                      char* __restrict__ ws)
{
  __shared__ __align__(16) unsigned short sH[4096];    // 8 KB staged pool h-hi, swizzled
  __shared__ float sC[16][17];                         // padded c-state
  __shared__ int sAsg[3][64];

  const int tid  = threadIdx.x;
  const int lane = tid & 63;
  const int lg   = lane >> 4;
  const int lc   = lane & 15;
  const int wv   = tid >> 6;        // 0..7
  const int cell = wv & 1;
  const int jq   = wv >> 1;         // j-quarter 0..3
  const int wg   = blockIdx.x;      // 0..63
  const int jset = wg & 15;         // owns j in [jset*16, jset*16+16)
  const int pool = wg >> 4;         // token pool 0..3 (16 tokens)

  unsigned int* hbuf = (unsigned int*)(ws + WS_H_OFF);
  const float* xg = (const float*)(ws + WS_XG_OFF);

  // ---- Whh A-frags hi/lo, rows ordered m=(j_sub<<2)|gate (update-ready) ----
  short8 aHiH[8], aLoH[8];
  {
    const float* ph = Whh + ((size_t)cell * G4 + (lc & 3) * HH
                             + jset * 16 + jq * 4 + (lc >> 2)) * HH + lg * 8;
    #pragma unroll
    for (int kc = 0; kc < 8; ++kc){
      const f32x4 u = *(const f32x4*)(ph + kc * 32);
      const f32x4 v = *(const f32x4*)(ph + kc * 32 + 4);
      short8 hi, lo;
      #pragma unroll
      for (int e = 0; e < 4; ++e){
        const float w0 = u[e], w1 = v[e];
        const unsigned short h0 = f2bf(w0), h1 = f2bf(w1);
        hi[e] = (short)h0;   lo[e] = (short)f2bf(w0 - bf2f(h0));
        hi[4+e] = (short)h1; lo[4+e] = (short)f2bf(w1 - bf2f(h1));
      }
      aHiH[kc] = hi; aLoH[kc] = lo;
    }
  }

  if (tid < 64){
    const int t0 = input[tid * SS];     sAsg[0][tid] = assign[t0];
    const int t1 = input[tid * SS + 1]; sAsg[1][tid] = assign[t1];
  }

  const int jloc   = jq * 4 + lg;         // 0..15
  const int jglob  = jset * 16 + jloc;
  const int b_loc  = lc;                  // 0..15 within pool
  const int b_glob = pool * 16 + lc;

  float xpre[4];
  auto XPRE = [&](int t){
    const float* p = xg + (size_t)t * 65536 + jglob * 64 + b_glob;
    #pragma unroll
    for (int q = 0; q < 4; ++q)
      xpre[q] = p[q * 16384];
  };
  XPRE(0);
  __syncthreads();

  for (int t = 0; t < SS; ++t){
    // ---- acc init from xg; prefetch next step + routing ----
    f32x4 acc;
    #pragma unroll
    for (int q = 0; q < 4; ++q) acc[q] = xpre[q];
    if (t + 1 < SS) XPRE(t + 1);
    if (t + 2 < SS && tid < 64){
      const int tk = input[tid * SS + (t + 2)];
      sAsg[(t + 2) % 3][tid] = assign[tk];
    }

    // ---- acquire pool h(t): per-thread validation spin (poll == load) ----
    if (t > 0){
      const unsigned int* bw = hbuf + (size_t)(t & 1) * 16384 + pool * 4096;
      const unsigned int need = (unsigned int)t;

      uint4v h0, h1;
      unsigned bad;
      const unsigned int* p0 = bw + tid * 8;
      do {
        asm volatile("global_load_dwordx4 %0, %1, off sc0 sc1" : "=v"(h0) : "v"(p0)     : "memory");
        asm volatile("global_load_dwordx4 %0, %1, off sc0 sc1" : "=v"(h1) : "v"(p0 + 4) : "memory");
        asm volatile("s_waitcnt vmcnt(0)" ::: "memory");
        bad = 0;
        #pragma unroll
        for (int e = 0; e < 4; ++e){ bad |= (h0[e] ^ need); bad |= (h1[e] ^ need); }
        bad &= 0xFFFFu;
        if (bad) __builtin_amdgcn_s_sleep(1);
      } while (bad);
      __builtin_amdgcn_sched_barrier(0);

      // pack hi16 -> 8 shorts (16B); LDS short-index == pool dword-index
      uint4v pk;
      pk[0] = (h0[0] >> 16) | (h0[1] & 0xFFFF0000u);
      pk[1] = (h0[2] >> 16) | (h0[3] & 0xFFFF0000u);
      pk[2] = (h1[0] >> 16) | (h1[1] & 0xFFFF0000u);
      pk[3] = (h1[2] >> 16) | (h1[3] & 0xFFFF0000u);
      *(uint4v*)((char*)sH + swz3(tid * 16)) = pk;
      __syncthreads();
    }

    // ---- h-part MFMAs: (Whi + Wlo)·h_hi, 16 per wave ----
    if (t > 0){
      #pragma unroll
      for (int kch = 0; kch < 8; ++kch){
        const int js = kch * 2 + (lg >> 1);
        const int byte = js * 512 + lc * 32 + (lg & 1) * 16;
        const short8 hh = *(const short8*)((const char*)sH + swz3(byte));
        acc = __builtin_amdgcn_mfma_f32_16x16x32_bf16(aHiH[kch], hh, acc, 0, 0, 0);
        acc = __builtin_amdgcn_mfma_f32_16x16x32_bf16(aLoH[kch], hh, acc, 0, 0, 0);
      }
    }

    // ---- in-register update + direct per-lane publish ----
    {
      const int a = sAsg[t % 3][b_glob];
      if (a == cell){
        const float gi = acc[0], gf = acc[1], gg = acc[2], go = acc[3];
        const float cold = (t == 0) ? 0.f : sC[b_loc][jloc];
        const float si = 1.f / (1.f + __expf(-gi));
        const float sf = 1.f / (1.f + __expf(-gf));
        const float so = 1.f / (1.f + __expf(-go));
        const float cn = sf * cold + si * tanhf(gg);
        const float hn = so * tanhf(cn);
        if (t < SS - 1){
          sC[b_loc][jloc] = cn;
          const unsigned word = ((unsigned)f2bf(hn) << 16) | ((unsigned)(t + 1) & 0xFFFFu);
          unsigned int* dst = hbuf + (size_t)((t & 1) ^ 1) * 16384 + pool * 4096
                            + jset * 256 + b_loc * 16 + jloc;
          asm volatile("global_store_dword %0, %1, off sc0 sc1" :: "v"(dst), "v"(word) : "memory");
        } else {
          out[b_glob * 512 + jglob]       = hn;
          out[b_glob * 512 + 256 + jglob] = cn;
        }
      }
    }
    // no publish barrier: next step's validation is the sync (induction-safe).
  }
}

extern "C" void kernel_launch(void* const* d_in, const int* in_sizes, int n_in,
                              void* d_out, int out_size, void* d_ws, size_t ws_size,
                              hipStream_t stream)
{
  const int*   input  = (const int*)  d_in[0];
  const int*   assign = (const int*)  d_in[1];
  const float* emb    = (const float*)d_in[2];
  const float* Wih    = (const float*)d_in[3];
  const float* Whh    = (const float*)d_in[4];
  const float* bih    = (const float*)d_in[5];
  const float* bhh    = (const float*)d_in[6];
  float* out = (float*)d_out;
  char*  ws  = (char*)d_ws;

  zero_ws_kernel<<<64, 256, 0, stream>>>((int*)ws);
  float* xg = (float*)(ws + WS_XG_OFF);
  xproj_kernel<<<512, TPB, 0, stream>>>(input, assign, emb, Wih, bih, bhh, xg);
  mlstm_rec_kernel<<<NWG, TPB, 0, stream>>>(input, assign, Whh, out, ws);
}

// Round 16
// 1092.584 us; speedup vs baseline: 3.5066x; 1.0180x over previous
//
#include <hip/hip_runtime.h>
#include <stdint.h>
#include <stddef.h>

// Routed 2-cell LSTM, B=64, S=512, E=H=256.
// FUSED kernel: blocks 0-63 = recurrence (round-15 protocol, byte-identical);
// blocks 64-255 = x-projection workers, grid-striding 512 (rowtile,tc) tiles
// in t-ascending order so early chunks finish first. xg stored sc0 sc1
// (IF-coherent: rec reads cross-XCD mid-kernel) + per-tile done flag
// (ushort, sc0 sc1, after vmcnt(0)+barrier). Rec gates its xg prefetch on
// the 16 tile flags of the next 16-step chunk (once per 16 steps).
// Rec exchange = validation-loop-as-poll: h = {bf16<<16|epoch16} dword;
// spin {2x dwordx4, one vmcnt, validate 8 epochs}; direct per-lane publish.
// Numerics bit-identical to rounds 13-15.

#define BB   64
#define SS   512
#define EE   256
#define HH   256
#define G4   1024
#define NREC 64
#define NB   256
#define TPB  512
#define TCH  16

typedef __attribute__((ext_vector_type(8))) short short8;
typedef __attribute__((ext_vector_type(4))) float f32x4;
typedef __attribute__((ext_vector_type(4))) unsigned int uint4v;

__device__ __forceinline__ unsigned short f2bf(float f){
  union { float f; unsigned u; } v; v.f = f;
  return (unsigned short)((v.u + 0x7fffu + ((v.u >> 16) & 1u)) >> 16);
}
__device__ __forceinline__ float bf2f(unsigned short s){
  union { float f; unsigned u; } v; v.u = ((unsigned)s) << 16;
  return v.f;
}
__device__ __forceinline__ int swz3(int byte){ return byte ^ (((byte >> 7) & 3) << 4); }

// ws layout (bytes):
// [0,1024)             : done[512] ushort tile flags (tile = tc*16+rowtile)
// [1024, +131072)      : h dwords {bf16<<16|epoch}, 2 parities x 16384 dwords;
//                        within parity: pool*4096 + jset*256 + b_loc*16 + jl
// [132096, +134217728) : xg[t=512][g=1024][b=64] fp32 (routed-cell gates)
#define WS_H_OFF  1024
#define WS_XG_OFF (1024 + 131072)

__global__ void zero_ws_kernel(int* ws){
  const int n = (WS_H_OFF + 131072) / 4;
  for (int i = blockIdx.x * blockDim.x + threadIdx.x; i < n; i += gridDim.x * blockDim.x){
    int* p = ws + i;
    const int z = 0;
    asm volatile("global_store_dword %0, %1, off sc0 sc1" :: "v"(p), "v"(z) : "memory");
  }
}

// ---------------- Fused: rec (blocks 0-63) + xproj (blocks 64-255) ----------------
__global__ __launch_bounds__(TPB, 1)
void mlstm_fused_kernel(const int* __restrict__ input, const int* __restrict__ assign,
                        const float* __restrict__ emb, const float* __restrict__ Wih,
                        const float* __restrict__ Whh, const float* __restrict__ bih,
                        const float* __restrict__ bhh, float* __restrict__ out,
                        char* __restrict__ ws)
{
  // xproj-role shared
  __shared__ __align__(16) unsigned short sXp[8][4][4][16][8];  // 32 KB
  __shared__ int sTokP[TCH][64];
  __shared__ int sAsgP[TCH][64];
  // rec-role shared
  __shared__ __align__(16) unsigned short sH[4096];             // 8 KB
  __shared__ float sC[16][17];
  __shared__ int sAsg[3][64];
  // occupancy pad: force 1 block/CU (total LDS > 80 KB)
  __shared__ char sPad[40960];

  const int tid  = threadIdx.x;
  const int lane = tid & 63;
  const int lg   = lane >> 4;
  const int lc   = lane & 15;
  const int wv   = tid >> 6;

  unsigned short* done = (unsigned short*)ws;
  unsigned int* hbuf = (unsigned int*)(ws + WS_H_OFF);
  float* xg = (float*)(ws + WS_XG_OFF);

  if (tid == 1) ((volatile char*)sPad)[0] = 0;

  if (blockIdx.x >= NREC){
    // ================= xproj role =================
    for (int tau = blockIdx.x - NREC; tau < 512; tau += (NB - NREC)){
      const int tc      = tau >> 4;
      const int rowtile = tau & 15;

      const int rbase = rowtile * 128 + wv * 16;
      const int cellw = rbase >> 10;
      const int rrw   = rbase & 1023;

      short8 aX[8];
      {
        const float* pw = Wih + ((size_t)cellw * G4 + (rrw + lc)) * EE + lg * 8;
        #pragma unroll
        for (int kc = 0; kc < 8; ++kc){
          const f32x4 u = *(const f32x4*)(pw + kc * 32);
          const f32x4 v = *(const f32x4*)(pw + kc * 32 + 4);
          short8 x8;
          #pragma unroll
          for (int e = 0; e < 4; ++e){ x8[e] = (short)f2bf(u[e]); x8[4+e] = (short)f2bf(v[e]); }
          aX[kc] = x8;
        }
      }
      float biasr[4];
      #pragma unroll
      for (int q = 0; q < 4; ++q){
        const int idx = cellw * G4 + rrw + lg * 4 + q;
        biasr[q] = bih[idx] + bhh[idx];
      }

      for (int i = tid; i < TCH * 64; i += TPB){
        const int tl = i >> 6, b = i & 63;
        const int tok = input[b * SS + tc * TCH + tl];
        sTokP[tl][b] = tok; sAsgP[tl][b] = assign[tok];
      }
      __syncthreads();

      const int gkc = tid >> 6, glg = (tid >> 4) & 3, glc = tid & 15;
      short8 xr[4];
      auto GATHERP = [&](int tl){
        #pragma unroll
        for (int ct = 0; ct < 4; ++ct){
          const int tok = sTokP[tl][ct * 16 + glc];
          const float* ep = emb + (size_t)tok * EE + gkc * 32 + glg * 8;
          const f32x4 u = *(const f32x4*)ep;
          const f32x4 v = *(const f32x4*)(ep + 4);
          short8 x8;
          #pragma unroll
          for (int e = 0; e < 4; ++e){ x8[e] = (short)f2bf(u[e]); x8[4+e] = (short)f2bf(v[e]); }
          xr[ct] = x8;
        }
      };
      GATHERP(0);

      for (int tl = 0; tl < TCH; ++tl){
        #pragma unroll
        for (int ct = 0; ct < 4; ++ct)
          *(short8*)&sXp[gkc][glg][ct][glc][0] = xr[ct];
        __syncthreads();
        if (tl + 1 < TCH) GATHERP(tl + 1);

        f32x4 acc[4];
        #pragma unroll
        for (int ct = 0; ct < 4; ++ct){
          acc[ct][0] = biasr[0]; acc[ct][1] = biasr[1];
          acc[ct][2] = biasr[2]; acc[ct][3] = biasr[3];
        }
        #pragma unroll
        for (int kc = 0; kc < 8; ++kc){
          #pragma unroll
          for (int ct = 0; ct < 4; ++ct){
            const short8 bx = *(const short8*)&sXp[kc][lg][ct][lc][0];
            acc[ct] = __builtin_amdgcn_mfma_f32_16x16x32_bf16(aX[kc], bx, acc[ct], 0, 0, 0);
          }
        }
        float* xgt = xg + (size_t)(tc * TCH + tl) * 65536;
        #pragma unroll
        for (int ct = 0; ct < 4; ++ct){
          const int b = ct * 16 + lc;
          if (sAsgP[tl][b] == cellw){
            #pragma unroll
            for (int q = 0; q < 4; ++q){
              float* dst = xgt + (rrw + lg * 4 + q) * 64 + b;
              const float val = acc[ct][q];
              asm volatile("global_store_dword %0, %1, off sc0 sc1" :: "v"(dst), "v"(val) : "memory");
            }
          }
        }
        __syncthreads();
      }

      // release tile: all xg stores ack'd at IF, then flag
      asm volatile("s_waitcnt vmcnt(0)" ::: "memory");
      __syncthreads();
      if (tid == 0){
        unsigned short* fp = done + tau;
        const unsigned one = 1;
        asm volatile("global_store_short %0, %1, off sc0 sc1" :: "v"(fp), "v"(one) : "memory");
      }
    }
    return;
  }

  // ================= rec role (round-15 protocol, frozen) =================
  const int cell = wv & 1;
  const int jq   = wv >> 1;
  const int wg   = blockIdx.x;      // 0..63
  const int jset = wg & 15;
  const int pool = wg >> 4;

  short8 aHiH[8], aLoH[8];
  {
    const float* ph = Whh + ((size_t)cell * G4 + (lc & 3) * HH
                             + jset * 16 + jq * 4 + (lc >> 2)) * HH + lg * 8;
    #pragma unroll
    for (int kc = 0; kc < 8; ++kc){
      const f32x4 u = *(const f32x4*)(ph + kc * 32);
      const f32x4 v = *(const f32x4*)(ph + kc * 32 + 4);
      short8 hi, lo;
      #pragma unroll
      for (int e = 0; e < 4; ++e){
        const float w0 = u[e], w1 = v[e];
        const unsigned short h0 = f2bf(w0), h1 = f2bf(w1);
        hi[e] = (short)h0;   lo[e] = (short)f2bf(w0 - bf2f(h0));
        hi[4+e] = (short)h1; lo[4+e] = (short)f2bf(w1 - bf2f(h1));
      }
      aHiH[kc] = hi; aLoH[kc] = lo;
    }
  }

  if (tid < 64){
    const int t0 = input[tid * SS];     sAsg[0][tid] = assign[t0];
    const int t1 = input[tid * SS + 1]; sAsg[1][tid] = assign[t1];
  }

  const int jloc   = jq * 4 + lg;
  const int jglob  = jset * 16 + jloc;
  const int b_loc  = lc;
  const int b_glob = pool * 16 + lc;

  float xpre[4];
  auto XPRE = [&](int t){
    const float* p = xg + (size_t)t * 65536 + jglob * 64 + b_glob;
    #pragma unroll
    for (int q = 0; q < 4; ++q)
      xpre[q] = p[q * 16384];
  };
  auto WAITCHUNK = [&](int c){
    const unsigned short* dp = done + c * 16 + (lane & 15);
    int ok;
    do {
      unsigned v;
      asm volatile("global_load_ushort %0, %1, off sc0 sc1\n\ts_waitcnt vmcnt(0)"
                   : "=v"(v) : "v"(dp) : "memory");
      ok = (__ballot(v != 1u) == 0ull);
      if (!ok) __builtin_amdgcn_s_sleep(8);
    } while (!ok);
  };

  WAITCHUNK(0);
  XPRE(0);
  __syncthreads();

  for (int t = 0; t < SS; ++t){
    // ---- acc init from xg; gated prefetch of next step + routing ----
    f32x4 acc;
    #pragma unroll
    for (int q = 0; q < 4; ++q) acc[q] = xpre[q];
    if (t + 1 < SS){
      if (((t + 1) & 15) == 0) WAITCHUNK((t + 1) >> 4);
      XPRE(t + 1);
    }
    if (t + 2 < SS && tid < 64){
      const int tk = input[tid * SS + (t + 2)];
      sAsg[(t + 2) % 3][tid] = assign[tk];
    }

    // ---- acquire pool h(t): per-thread validation spin (poll == load) ----
    if (t > 0){
      const unsigned int* bw = hbuf + (size_t)(t & 1) * 16384 + pool * 4096;
      const unsigned int need = (unsigned int)t;

      uint4v h0, h1;
      unsigned bad;
      const unsigned int* p0 = bw + tid * 8;
      do {
        asm volatile("global_load_dwordx4 %0, %1, off sc0 sc1" : "=v"(h0) : "v"(p0)     : "memory");
        asm volatile("global_load_dwordx4 %0, %1, off sc0 sc1" : "=v"(h1) : "v"(p0 + 4) : "memory");
        asm volatile("s_waitcnt vmcnt(0)" ::: "memory");
        bad = 0;
        #pragma unroll
        for (int e = 0; e < 4; ++e){ bad |= (h0[e] ^ need); bad |= (h1[e] ^ need); }
        bad &= 0xFFFFu;
        if (bad) __builtin_amdgcn_s_sleep(1);
      } while (bad);
      __builtin_amdgcn_sched_barrier(0);

      uint4v pk;
      pk[0] = (h0[0] >> 16) | (h0[1] & 0xFFFF0000u);
      pk[1] = (h0[2] >> 16) | (h0[3] & 0xFFFF0000u);
      pk[2] = (h1[0] >> 16) | (h1[1] & 0xFFFF0000u);
      pk[3] = (h1[2] >> 16) | (h1[3] & 0xFFFF0000u);
      *(uint4v*)((char*)sH + swz3(tid * 16)) = pk;
      __syncthreads();
    }

    // ---- h-part MFMAs: (Whi + Wlo)·h_hi, 16 per wave ----
    if (t > 0){
      #pragma unroll
      for (int kch = 0; kch < 8; ++kch){
        const int js = kch * 2 + (lg >> 1);
        const int byte = js * 512 + lc * 32 + (lg & 1) * 16;
        const short8 hh = *(const short8*)((const char*)sH + swz3(byte));
        acc = __builtin_amdgcn_mfma_f32_16x16x32_bf16(aHiH[kch], hh, acc, 0, 0, 0);
        acc = __builtin_amdgcn_mfma_f32_16x16x32_bf16(aLoH[kch], hh, acc, 0, 0, 0);
      }
    }

    // ---- in-register update + direct per-lane publish ----
    {
      const int a = sAsg[t % 3][b_glob];
      if (a == cell){
        const float gi = acc[0], gf = acc[1], gg = acc[2], go = acc[3];
        const float cold = (t == 0) ? 0.f : sC[b_loc][jloc];
        const float si = 1.f / (1.f + __expf(-gi));
        const float sf = 1.f / (1.f + __expf(-gf));
        const float so = 1.f / (1.f + __expf(-go));
        const float cn = sf * cold + si * tanhf(gg);
        const float hn = so * tanhf(cn);
        if (t < SS - 1){
          sC[b_loc][jloc] = cn;
          const unsigned word = ((unsigned)f2bf(hn) << 16) | ((unsigned)(t + 1) & 0xFFFFu);
          unsigned int* dst = hbuf + (size_t)((t & 1) ^ 1) * 16384 + pool * 4096
                            + jset * 256 + b_loc * 16 + jloc;
          asm volatile("global_store_dword %0, %1, off sc0 sc1" :: "v"(dst), "v"(word) : "memory");
        } else {
          out[b_glob * 512 + jglob]       = hn;
          out[b_glob * 512 + 256 + jglob] = cn;
        }
      }
    }
    // no publish barrier: next step's validation is the sync (induction-safe).
  }
}

extern "C" void kernel_launch(void* const* d_in, const int* in_sizes, int n_in,
                              void* d_out, int out_size, void* d_ws, size_t ws_size,
                              hipStream_t stream)
{
  const int*   input  = (const int*)  d_in[0];
  const int*   assign = (const int*)  d_in[1];
  const float* emb    = (const float*)d_in[2];
  const float* Wih    = (const float*)d_in[3];
  const float* Whh    = (const float*)d_in[4];
  const float* bih    = (const float*)d_in[5];
  const float* bhh    = (const float*)d_in[6];
  float* out = (float*)d_out;
  char*  ws  = (char*)d_ws;

  zero_ws_kernel<<<64, 256, 0, stream>>>((int*)ws);
  mlstm_fused_kernel<<<NB, TPB, 0, stream>>>(input, assign, emb, Wih, Whh,
                                             bih, bhh, out, ws);
}

// Round 17
// 1031.730 us; speedup vs baseline: 3.7134x; 1.0590x over previous
//
#include <hip/hip_runtime.h>
#include <stdint.h>
#include <stddef.h>

// Routed 2-cell LSTM, B=64, S=512, E=H=256.
// FUSED kernel: blocks 0-63 = recurrence (round-15 protocol, frozen);
// blocks 64-255 = x-projection workers, grid-striding 512 (rowtile,tc) tiles
// in t-ascending order. xg stored as BF16 (ushort, sc0 sc1 write-through:
// halves IF write traffic vs fp32 -> less contention on the rec critical
// path) + per-tile done flag (sc0 sc1 after vmcnt(0)+barrier). Rec gates its
// xg prefetch on the 16 tile flags of the next 16-step chunk.
// Rec exchange = validation-loop-as-poll: h = {bf16<<16|epoch16} dword;
// spin {2x dwordx4, one vmcnt, validate 8 epochs}; direct per-lane publish.
// Only numerics change vs rounds 13-16: xg quantized to bf16 (x-part preact,
// |val|<~0.1 -> ~2e-4 abs err; h-bf16 precedent showed absmax unchanged).

#define BB   64
#define SS   512
#define EE   256
#define HH   256
#define G4   1024
#define NREC 64
#define NB   256
#define TPB  512
#define TCH  16

typedef __attribute__((ext_vector_type(8))) short short8;
typedef __attribute__((ext_vector_type(4))) float f32x4;
typedef __attribute__((ext_vector_type(4))) unsigned int uint4v;

__device__ __forceinline__ unsigned short f2bf(float f){
  union { float f; unsigned u; } v; v.f = f;
  return (unsigned short)((v.u + 0x7fffu + ((v.u >> 16) & 1u)) >> 16);
}
__device__ __forceinline__ float bf2f(unsigned short s){
  union { float f; unsigned u; } v; v.u = ((unsigned)s) << 16;
  return v.f;
}
__device__ __forceinline__ int swz3(int byte){ return byte ^ (((byte >> 7) & 3) << 4); }

// ws layout (bytes):
// [0,1024)             : done[512] ushort tile flags (tile = tc*16+rowtile)
// [1024, +131072)      : h dwords {bf16<<16|epoch}, 2 parities x 16384 dwords;
//                        within parity: pool*4096 + jset*256 + b_loc*16 + jl
// [132096, +67108864)  : xg[t=512][g=1024][b=64] BF16 ushort (routed-cell gates)
#define WS_H_OFF  1024
#define WS_XG_OFF (1024 + 131072)

__global__ void zero_ws_kernel(int* ws){
  const int n = (WS_H_OFF + 131072) / 4;
  for (int i = blockIdx.x * blockDim.x + threadIdx.x; i < n; i += gridDim.x * blockDim.x){
    int* p = ws + i;
    const int z = 0;
    asm volatile("global_store_dword %0, %1, off sc0 sc1" :: "v"(p), "v"(z) : "memory");
  }
}

// ---------------- Fused: rec (blocks 0-63) + xproj (blocks 64-255) ----------------
__global__ __launch_bounds__(TPB, 1)
void mlstm_fused_kernel(const int* __restrict__ input, const int* __restrict__ assign,
                        const float* __restrict__ emb, const float* __restrict__ Wih,
                        const float* __restrict__ Whh, const float* __restrict__ bih,
                        const float* __restrict__ bhh, float* __restrict__ out,
                        char* __restrict__ ws)
{
  // xproj-role shared
  __shared__ __align__(16) unsigned short sXp[8][4][4][16][8];  // 32 KB
  __shared__ int sTokP[TCH][64];
  __shared__ int sAsgP[TCH][64];
  // rec-role shared
  __shared__ __align__(16) unsigned short sH[4096];             // 8 KB
  __shared__ float sC[16][17];
  __shared__ int sAsg[3][64];
  // occupancy pad: force 1 block/CU (total LDS > 80 KB)
  __shared__ char sPad[40960];

  const int tid  = threadIdx.x;
  const int lane = tid & 63;
  const int lg   = lane >> 4;
  const int lc   = lane & 15;
  const int wv   = tid >> 6;

  unsigned short* done = (unsigned short*)ws;
  unsigned int* hbuf = (unsigned int*)(ws + WS_H_OFF);
  unsigned short* xg = (unsigned short*)(ws + WS_XG_OFF);

  if (tid == 1) ((volatile char*)sPad)[0] = 0;

  if (blockIdx.x >= NREC){
    // ================= xproj role =================
    for (int tau = blockIdx.x - NREC; tau < 512; tau += (NB - NREC)){
      const int tc      = tau >> 4;
      const int rowtile = tau & 15;

      const int rbase = rowtile * 128 + wv * 16;
      const int cellw = rbase >> 10;
      const int rrw   = rbase & 1023;

      short8 aX[8];
      {
        const float* pw = Wih + ((size_t)cellw * G4 + (rrw + lc)) * EE + lg * 8;
        #pragma unroll
        for (int kc = 0; kc < 8; ++kc){
          const f32x4 u = *(const f32x4*)(pw + kc * 32);
          const f32x4 v = *(const f32x4*)(pw + kc * 32 + 4);
          short8 x8;
          #pragma unroll
          for (int e = 0; e < 4; ++e){ x8[e] = (short)f2bf(u[e]); x8[4+e] = (short)f2bf(v[e]); }
          aX[kc] = x8;
        }
      }
      float biasr[4];
      #pragma unroll
      for (int q = 0; q < 4; ++q){
        const int idx = cellw * G4 + rrw + lg * 4 + q;
        biasr[q] = bih[idx] + bhh[idx];
      }

      for (int i = tid; i < TCH * 64; i += TPB){
        const int tl = i >> 6, b = i & 63;
        const int tok = input[b * SS + tc * TCH + tl];
        sTokP[tl][b] = tok; sAsgP[tl][b] = assign[tok];
      }
      __syncthreads();

      const int gkc = tid >> 6, glg = (tid >> 4) & 3, glc = tid & 15;
      short8 xr[4];
      auto GATHERP = [&](int tl){
        #pragma unroll
        for (int ct = 0; ct < 4; ++ct){
          const int tok = sTokP[tl][ct * 16 + glc];
          const float* ep = emb + (size_t)tok * EE + gkc * 32 + glg * 8;
          const f32x4 u = *(const f32x4*)ep;
          const f32x4 v = *(const f32x4*)(ep + 4);
          short8 x8;
          #pragma unroll
          for (int e = 0; e < 4; ++e){ x8[e] = (short)f2bf(u[e]); x8[4+e] = (short)f2bf(v[e]); }
          xr[ct] = x8;
        }
      };
      GATHERP(0);

      for (int tl = 0; tl < TCH; ++tl){
        #pragma unroll
        for (int ct = 0; ct < 4; ++ct)
          *(short8*)&sXp[gkc][glg][ct][glc][0] = xr[ct];
        __syncthreads();
        if (tl + 1 < TCH) GATHERP(tl + 1);

        f32x4 acc[4];
        #pragma unroll
        for (int ct = 0; ct < 4; ++ct){
          acc[ct][0] = biasr[0]; acc[ct][1] = biasr[1];
          acc[ct][2] = biasr[2]; acc[ct][3] = biasr[3];
        }
        #pragma unroll
        for (int kc = 0; kc < 8; ++kc){
          #pragma unroll
          for (int ct = 0; ct < 4; ++ct){
            const short8 bx = *(const short8*)&sXp[kc][lg][ct][lc][0];
            acc[ct] = __builtin_amdgcn_mfma_f32_16x16x32_bf16(aX[kc], bx, acc[ct], 0, 0, 0);
          }
        }
        unsigned short* xgt = xg + (size_t)(tc * TCH + tl) * 65536;
        #pragma unroll
        for (int ct = 0; ct < 4; ++ct){
          const int b = ct * 16 + lc;
          if (sAsgP[tl][b] == cellw){
            #pragma unroll
            for (int q = 0; q < 4; ++q){
              unsigned short* dst = xgt + (rrw + lg * 4 + q) * 64 + b;
              const unsigned val = f2bf(acc[ct][q]);
              asm volatile("global_store_short %0, %1, off sc0 sc1" :: "v"(dst), "v"(val) : "memory");
            }
          }
        }
        __syncthreads();
      }

      // release tile: all xg stores ack'd at IF, then flag
      asm volatile("s_waitcnt vmcnt(0)" ::: "memory");
      __syncthreads();
      if (tid == 0){
        unsigned short* fp = done + tau;
        const unsigned one = 1;
        asm volatile("global_store_short %0, %1, off sc0 sc1" :: "v"(fp), "v"(one) : "memory");
      }
    }
    return;
  }

  // ================= rec role (round-15 protocol, frozen) =================
  const int cell = wv & 1;
  const int jq   = wv >> 1;
  const int wg   = blockIdx.x;      // 0..63
  const int jset = wg & 15;
  const int pool = wg >> 4;

  short8 aHiH[8], aLoH[8];
  {
    const float* ph = Whh + ((size_t)cell * G4 + (lc & 3) * HH
                             + jset * 16 + jq * 4 + (lc >> 2)) * HH + lg * 8;
    #pragma unroll
    for (int kc = 0; kc < 8; ++kc){
      const f32x4 u = *(const f32x4*)(ph + kc * 32);
      const f32x4 v = *(const f32x4*)(ph + kc * 32 + 4);
      short8 hi, lo;
      #pragma unroll
      for (int e = 0; e < 4; ++e){
        const float w0 = u[e], w1 = v[e];
        const unsigned short h0 = f2bf(w0), h1 = f2bf(w1);
        hi[e] = (short)h0;   lo[e] = (short)f2bf(w0 - bf2f(h0));
        hi[4+e] = (short)h1; lo[4+e] = (short)f2bf(w1 - bf2f(h1));
      }
      aHiH[kc] = hi; aLoH[kc] = lo;
    }
  }

  if (tid < 64){
    const int t0 = input[tid * SS];     sAsg[0][tid] = assign[t0];
    const int t1 = input[tid * SS + 1]; sAsg[1][tid] = assign[t1];
  }

  const int jloc   = jq * 4 + lg;
  const int jglob  = jset * 16 + jloc;
  const int b_loc  = lc;
  const int b_glob = pool * 16 + lc;

  float xpre[4];
  auto XPRE = [&](int t){
    const unsigned short* p = xg + (size_t)t * 65536 + jglob * 64 + b_glob;
    #pragma unroll
    for (int q = 0; q < 4; ++q)
      xpre[q] = bf2f(p[q * 16384]);
  };
  auto WAITCHUNK = [&](int c){
    const unsigned short* dp = done + c * 16 + (lane & 15);
    int ok;
    do {
      unsigned v;
      asm volatile("global_load_ushort %0, %1, off sc0 sc1\n\ts_waitcnt vmcnt(0)"
                   : "=v"(v) : "v"(dp) : "memory");
      ok = (__ballot(v != 1u) == 0ull);
      if (!ok) __builtin_amdgcn_s_sleep(8);
    } while (!ok);
  };

  WAITCHUNK(0);
  XPRE(0);
  __syncthreads();

  for (int t = 0; t < SS; ++t){
    // ---- acc init from xg; gated prefetch of next step + routing ----
    f32x4 acc;
    #pragma unroll
    for (int q = 0; q < 4; ++q) acc[q] = xpre[q];
    if (t + 1 < SS){
      if (((t + 1) & 15) == 0) WAITCHUNK((t + 1) >> 4);
      XPRE(t + 1);
    }
    if (t + 2 < SS && tid < 64){
      const int tk = input[tid * SS + (t + 2)];
      sAsg[(t + 2) % 3][tid] = assign[tk];
    }

    // ---- acquire pool h(t): per-thread validation spin (poll == load) ----
    if (t > 0){
      const unsigned int* bw = hbuf + (size_t)(t & 1) * 16384 + pool * 4096;
      const unsigned int need = (unsigned int)t;

      uint4v h0, h1;
      unsigned bad;
      const unsigned int* p0 = bw + tid * 8;
      do {
        asm volatile("global_load_dwordx4 %0, %1, off sc0 sc1" : "=v"(h0) : "v"(p0)     : "memory");
        asm volatile("global_load_dwordx4 %0, %1, off sc0 sc1" : "=v"(h1) : "v"(p0 + 4) : "memory");
        asm volatile("s_waitcnt vmcnt(0)" ::: "memory");
        bad = 0;
        #pragma unroll
        for (int e = 0; e < 4; ++e){ bad |= (h0[e] ^ need); bad |= (h1[e] ^ need); }
        bad &= 0xFFFFu;
        if (bad) __builtin_amdgcn_s_sleep(1);
      } while (bad);
      __builtin_amdgcn_sched_barrier(0);

      uint4v pk;
      pk[0] = (h0[0] >> 16) | (h0[1] & 0xFFFF0000u);
      pk[1] = (h0[2] >> 16) | (h0[3] & 0xFFFF0000u);
      pk[2] = (h1[0] >> 16) | (h1[1] & 0xFFFF0000u);
      pk[3] = (h1[2] >> 16) | (h1[3] & 0xFFFF0000u);
      *(uint4v*)((char*)sH + swz3(tid * 16)) = pk;
      __syncthreads();
    }

    // ---- h-part MFMAs: (Whi + Wlo)·h_hi, 16 per wave ----
    if (t > 0){
      #pragma unroll
      for (int kch = 0; kch < 8; ++kch){
        const int js = kch * 2 + (lg >> 1);
        const int byte = js * 512 + lc * 32 + (lg & 1) * 16;
        const short8 hh = *(const short8*)((const char*)sH + swz3(byte));
        acc = __builtin_amdgcn_mfma_f32_16x16x32_bf16(aHiH[kch], hh, acc, 0, 0, 0);
        acc = __builtin_amdgcn_mfma_f32_16x16x32_bf16(aLoH[kch], hh, acc, 0, 0, 0);
      }
    }

    // ---- in-register update + direct per-lane publish ----
    {
      const int a = sAsg[t % 3][b_glob];
      if (a == cell){
        const float gi = acc[0], gf = acc[1], gg = acc[2], go = acc[3];
        const float cold = (t == 0) ? 0.f : sC[b_loc][jloc];
        const float si = 1.f / (1.f + __expf(-gi));
        const float sf = 1.f / (1.f + __expf(-gf));
        const float so = 1.f / (1.f + __expf(-go));
        const float cn = sf * cold + si * tanhf(gg);
        const float hn = so * tanhf(cn);
        if (t < SS - 1){
          sC[b_loc][jloc] = cn;
          const unsigned word = ((unsigned)f2bf(hn) << 16) | ((unsigned)(t + 1) & 0xFFFFu);
          unsigned int* dst = hbuf + (size_t)((t & 1) ^ 1) * 16384 + pool * 4096
                            + jset * 256 + b_loc * 16 + jloc;
          asm volatile("global_store_dword %0, %1, off sc0 sc1" :: "v"(dst), "v"(word) : "memory");
        } else {
          out[b_glob * 512 + jglob]       = hn;
          out[b_glob * 512 + 256 + jglob] = cn;
        }
      }
    }
    // no publish barrier: next step's validation is the sync (induction-safe).
  }
}

extern "C" void kernel_launch(void* const* d_in, const int* in_sizes, int n_in,
                              void* d_out, int out_size, void* d_ws, size_t ws_size,
                              hipStream_t stream)
{
  const int*   input  = (const int*)  d_in[0];
  const int*   assign = (const int*)  d_in[1];
  const float* emb    = (const float*)d_in[2];
  const float* Wih    = (const float*)d_in[3];
  const float* Whh    = (const float*)d_in[4];
  const float* bih    = (const float*)d_in[5];
  const float* bhh    = (const float*)d_in[6];
  float* out = (float*)d_out;
  char*  ws  = (char*)d_ws;

  zero_ws_kernel<<<64, 256, 0, stream>>>((int*)ws);
  mlstm_fused_kernel<<<NB, TPB, 0, stream>>>(input, assign, emb, Wih, Whh,
                                             bih, bhh, out, ws);
}